// Round 1
// baseline (672.693 us; speedup 1.0000x reference)
//
#include <hip/hip_runtime.h>

#define NEGV (-100000000.0f)

constexpr int BB = 32, MM = 24, RR = 384, DD = 2048;

// ---------------- Kernel A: h0h1[row][0:16]=region@t0_w^T+t0_b, [16:32]=t1 ----
// grid 384 blocks x 256 thr; 32 rows/block; split-K over 8 thread-groups.
__global__ __launch_bounds__(256) void kA(const float* __restrict__ region,
    const float* __restrict__ t0w, const float* __restrict__ t0b,
    const float* __restrict__ t1w, const float* __restrict__ t1b,
    float* __restrict__ h0h1) {
  __shared__ float rlds[32][260];
  __shared__ float wlds[256][36];
  const int t = threadIdx.x;
  const int r = t & 31;
  const int q = t >> 5;
  const int row0 = blockIdx.x * 32;
  float acc[32];
#pragma unroll
  for (int h = 0; h < 32; ++h) acc[h] = 0.f;

  for (int tile = 0; tile < 8; ++tile) {
    const int d0 = tile * 256;
    __syncthreads();
#pragma unroll
    for (int i = 0; i < 8; ++i) {
      int flat = i * 256 + t;      // float4 index
      int rr2 = flat >> 6;
      int cc = (flat & 63) << 2;
      *(float4*)&rlds[rr2][cc] =
          *(const float4*)(region + (size_t)(row0 + rr2) * DD + d0 + cc);
    }
#pragma unroll
    for (int h = 0; h < 32; ++h) {
      const float* wsrc = (h < 16) ? (t0w + (size_t)h * DD)
                                   : (t1w + (size_t)(h - 16) * DD);
      wlds[t][h] = wsrc[d0 + t];
    }
    __syncthreads();
    const int djb = q * 32;
#pragma unroll 4
    for (int dj = djb; dj < djb + 32; ++dj) {
      float rv = rlds[r][dj];
      const float4* wp = (const float4*)&wlds[dj][0];
#pragma unroll
      for (int h4 = 0; h4 < 8; ++h4) {
        float4 wv = wp[h4];
        acc[h4 * 4 + 0] = fmaf(rv, wv.x, acc[h4 * 4 + 0]);
        acc[h4 * 4 + 1] = fmaf(rv, wv.y, acc[h4 * 4 + 1]);
        acc[h4 * 4 + 2] = fmaf(rv, wv.z, acc[h4 * 4 + 2]);
        acc[h4 * 4 + 3] = fmaf(rv, wv.w, acc[h4 * 4 + 3]);
      }
    }
  }
  __syncthreads();
  float* red = &wlds[0][0];        // reuse as [8][32][36]
#pragma unroll
  for (int h4 = 0; h4 < 8; ++h4) {
    *(float4*)&red[(q * 32 + r) * 36 + h4 * 4] =
        make_float4(acc[h4 * 4 + 0], acc[h4 * 4 + 1], acc[h4 * 4 + 2], acc[h4 * 4 + 3]);
  }
  __syncthreads();
  {
    const int r2 = t & 31;
    const int hb = (t >> 5) * 4;
    float s0 = 0, s1 = 0, s2 = 0, s3 = 0;
#pragma unroll
    for (int qq = 0; qq < 8; ++qq) {
      float4 v = *(const float4*)&red[(qq * 32 + r2) * 36 + hb];
      s0 += v.x; s1 += v.y; s2 += v.z; s3 += v.w;
    }
    float4 bias = (hb < 16) ? *(const float4*)(t0b + hb)
                            : *(const float4*)(t1b + hb - 16);
    *(float4*)(h0h1 + (size_t)(row0 + r2) * 32 + hb) =
        make_float4(s0 + bias.x, s1 + bias.y, s2 + bias.z, s3 + bias.w);
  }
}

// ---------------- Kernel C: reward / reward_log / active per (b,m) ----------
__global__ __launch_bounds__(128) void kC(const float* __restrict__ gt,
    const int* __restrict__ nmen, const int* __restrict__ nreg,
    float* __restrict__ reward, float* __restrict__ rlog,
    int* __restrict__ activ) {
  const int bm = blockIdx.x;          // b*24+m
  const int b = bm / 24, m = bm - b * 24;
  const int t = threadIdx.x;
  const bool menok = m < nmen[b];
  const int nr = nreg[b];
  float a[3];
  float part = 0.f;
#pragma unroll
  for (int i = 0; i < 3; ++i) {
    int r = t + i * 128;
    float g = gt[(size_t)bm * RR + r];
    float av = (g >= 0.5f && r < nr && menok) ? g : 0.f;
    a[i] = av;
    part += av;
  }
#pragma unroll
  for (int off = 32; off > 0; off >>= 1) part += __shfl_xor(part, off);
  __shared__ float wsum[2];
  __shared__ float stot;
  if ((t & 63) == 0) wsum[t >> 6] = part;
  __syncthreads();
  if (t == 0) stot = wsum[0] + wsum[1];
  __syncthreads();
  const float s = stot;
  const float inv = 1.f / (s > 0.f ? s : 1.f);
#pragma unroll
  for (int i = 0; i < 3; ++i) {
    int r = t + i * 128;
    float rw = a[i] * inv;
    reward[(size_t)bm * RR + r] = rw;
    rlog[(size_t)bm * RR + r] = (rw > 0.f) ? __logf(rw) : NEGV;
  }
  if (t == 0) activ[bm] = (s > 0.f && menok) ? 1 : 0;
}

// ---------------- Kernel C2: compact active-m lists ----------
__global__ void kC2(const int* __restrict__ activ, int* __restrict__ mlist,
                    int* __restrict__ kcnt) {
  const int t = threadIdx.x;
  if (t < 32) {
    int c = 0;
    for (int m = 0; m < 24; ++m)
      if (activ[t * 24 + m]) mlist[t * 24 + (c++)] = m;
    kcnt[t] = c;
  }
}

// ---------------- Kernel D: the scan. 256 blocks = 32 batches x 8 chunks ----
__global__ __launch_bounds__(256) void kD(
    const float* __restrict__ h0h1, const float* __restrict__ emit,
    const float* __restrict__ reward, const float* __restrict__ rlog,
    const int* __restrict__ nreg, const int* __restrict__ mlist,
    const int* __restrict__ kcnt, const float* __restrict__ trw,
    const float* __restrict__ trb,
    float* __restrict__ alphag, float* __restrict__ pmaxg,
    float* __restrict__ pdotg, unsigned* __restrict__ cnt,
    float* __restrict__ result) {
  __shared__ float tranL[48 * 384];
  __shared__ float expTL[48 * 384];
  __shared__ float Tmax[48];
  __shared__ float wred[4][2];
  __shared__ float sScal[2];

  const int bid = blockIdx.x;
  const int b = bid & 31;           // batch; chunk-major so 8 chunks share XCD
  const int chunk = bid >> 5;
  const int r0 = chunk * 48;
  const int tid = threadIdx.x;
  const int lane = tid & 63;
  const int w = tid >> 6;
  const int s4 = lane * 4;          // 4 consecutive s per lane
  const int s2 = 256 + lane * 2;    // + 2 more

  float* h1T = &expTL[18432 - 6144];  // transient [16][384] in expTL tail

  for (int i = tid; i < 6144; i += 256) {
    int h = i / 384, s = i - h * 384;
    h1T[i] = h0h1[((size_t)b * RR + s) * 32 + 16 + h];
  }
  float w0[16];
#pragma unroll
  for (int h4 = 0; h4 < 4; ++h4) {
    float4 v = *(const float4*)(trw + h4 * 4);
    w0[h4 * 4 + 0] = v.x; w0[h4 * 4 + 1] = v.y;
    w0[h4 * 4 + 2] = v.z; w0[h4 * 4 + 3] = v.w;
  }
  const float tb = trb[0];
  const int nregb = nreg[b];
  __syncthreads();

  // prologue: tran rows for my 48 r, row max
  for (int j = 0; j < 12; ++j) {
    const int row = w * 12 + j;
    const float* hp = h0h1 + ((size_t)b * RR + r0 + row) * 32;
    float h0v[16];
#pragma unroll
    for (int h4 = 0; h4 < 4; ++h4) {
      float4 v = *(const float4*)(hp + h4 * 4);
      h0v[h4 * 4 + 0] = v.x; h0v[h4 * 4 + 1] = v.y;
      h0v[h4 * 4 + 2] = v.z; h0v[h4 * 4 + 3] = v.w;
    }
    float a0 = tb, a1 = tb, a2 = tb, a3 = tb, a4 = tb, a5 = tb;
#pragma unroll
    for (int h = 0; h < 16; ++h) {
      const float* hbp = &h1T[h * 384];
      float4 v4 = *(const float4*)(hbp + s4);
      float2 v2 = *(const float2*)(hbp + s2);
      const float wv = w0[h], hx = h0v[h];
      a0 += fmaxf(hx + v4.x, 0.f) * wv;
      a1 += fmaxf(hx + v4.y, 0.f) * wv;
      a2 += fmaxf(hx + v4.z, 0.f) * wv;
      a3 += fmaxf(hx + v4.w, 0.f) * wv;
      a4 += fmaxf(hx + v2.x, 0.f) * wv;
      a5 += fmaxf(hx + v2.y, 0.f) * wv;
    }
    *(float4*)&tranL[row * 384 + s4] = make_float4(a0, a1, a2, a3);
    *(float2*)&tranL[row * 384 + s2] = make_float2(a4, a5);
    float mx = fmaxf(fmaxf(fmaxf(a0, a1), fmaxf(a2, a3)), fmaxf(a4, a5));
#pragma unroll
    for (int off = 32; off > 0; off >>= 1) mx = fmaxf(mx, __shfl_xor(mx, off));
    if (lane == 0) Tmax[row] = mx;
  }
  __syncthreads();
  for (int i = tid; i < 18432; i += 256)
    expTL[i] = __expf(tranL[i] - Tmax[i / 384]);   // overwrites h1T (dead)
  __syncthreads();

  const int K = kcnt[b];
  if (K == 0) {
    if (chunk == 0 && tid == 0) result[b] = 0.f;
    return;
  }

  float A = 0.f, dotp = 0.f;
  for (int k = 0; k < K; ++k) {
    const int m = mlist[b * MM + k];
    float xA0 = 0, xA1 = 0, xA2 = 0, xA3 = 0, xA4 = 0, xA5 = 0;
    float rp0 = 0, rp1 = 0, rp2 = 0, rp3 = 0, rp4 = 0, rp5 = 0;
    if (k > 0) {
      const int mp = mlist[b * MM + k - 1];
      const float* ap = alphag + ((k & 1) ^ 1) * (BB * RR) + b * RR;
      float4 av4 = *(const float4*)(ap + s4);
      float2 av2 = *(const float2*)(ap + s2);
      xA0 = __expf(av4.x - A); xA1 = __expf(av4.y - A);
      xA2 = __expf(av4.z - A); xA3 = __expf(av4.w - A);
      xA4 = __expf(av2.x - A); xA5 = __expf(av2.y - A);
      const float* rp = reward + ((size_t)b * MM + mp) * RR;
      float4 rv4 = *(const float4*)(rp + s4);
      float2 rv2 = *(const float2*)(rp + s2);
      rp0 = rv4.x; rp1 = rv4.y; rp2 = rv4.z; rp3 = rv4.w;
      rp4 = rv2.x; rp5 = rv2.y;
    }
    float eL = 0.f, rlL = 0.f, rwL = 0.f;
    if (lane < 12) {
      const int rr2 = r0 + w * 12 + lane;
      eL = emit[((size_t)b * MM + m) * RR + rr2];
      rlL = rlog[((size_t)b * MM + m) * RR + rr2];
      rwL = reward[((size_t)b * MM + m) * RR + rr2];
    }
    float pmax_w = -3.0e38f, pd_w = 0.f;
    float* abuf = alphag + (k & 1) * (BB * RR) + b * RR;
    for (int j = 0; j < 12; ++j) {
      const int row = w * 12 + j;
      const float ev = __shfl(eL, j);
      const float rlv = __shfl(rlL, j);
      const float rwv = __shfl(rwL, j);
      float alpha_new, score_new;
      if (k == 0) {
        alpha_new = ((r0 + row) < nregb ? 0.f : NEGV) + ev;
        score_new = ev - rlv;
      } else {
        const float* et = &expTL[row * 384];
        const float* tt = &tranL[row * 384];
        float4 e4 = *(const float4*)(et + s4);
        float2 e2 = *(const float2*)(et + s2);
        float4 t4 = *(const float4*)(tt + s4);
        float2 t2 = *(const float2*)(tt + s2);
        float asum = e4.x * xA0 + e4.y * xA1 + e4.z * xA2 + e4.w * xA3 +
                     e2.x * xA4 + e2.y * xA5;
        float tsum = t4.x * rp0 + t4.y * rp1 + t4.z * rp2 + t4.w * rp3 +
                     t2.x * rp4 + t2.y * rp5;
#pragma unroll
        for (int off = 32; off > 0; off >>= 1) {
          asum += __shfl_xor(asum, off);
          tsum += __shfl_xor(tsum, off);
        }
        alpha_new = Tmax[row] + A + __logf(asum) + ev;
        score_new = dotp + tsum + ev - rlv;
      }
      pmax_w = fmaxf(pmax_w, alpha_new);
      pd_w += score_new * rwv;
      if (lane == 0) abuf[r0 + row] = alpha_new;
    }
    if (lane == 0) { wred[w][0] = pmax_w; wred[w][1] = pd_w; }
    __threadfence();
    __syncthreads();
    if (tid == 0) {
      float bm = fmaxf(fmaxf(wred[0][0], wred[1][0]), fmaxf(wred[2][0], wred[3][0]));
      float bd = wred[0][1] + wred[1][1] + wred[2][1] + wred[3][1];
      float* pmv = pmaxg + (k & 1) * (BB * 8);
      float* pdv = pdotg + (k & 1) * (BB * 8);
      pmv[b * 8 + chunk] = bm;
      pdv[b * 8 + chunk] = bd;
      const unsigned cidx = (unsigned)(b * MM + k);
      __hip_atomic_fetch_add(&cnt[cidx], 1u, __ATOMIC_ACQ_REL, __HIP_MEMORY_SCOPE_AGENT);
      while (__hip_atomic_load(&cnt[cidx], __ATOMIC_ACQUIRE, __HIP_MEMORY_SCOPE_AGENT) < 8u)
        __builtin_amdgcn_s_sleep(16);
      float gm = -3.0e38f, gd = 0.f;
#pragma unroll
      for (int c = 0; c < 8; ++c) {
        gm = fmaxf(gm, pmv[b * 8 + c]);
        gd += pdv[b * 8 + c];
      }
      sScal[0] = gm; sScal[1] = gd;
    }
    __syncthreads();
    A = sScal[0];
    dotp = sScal[1];
  }

  if (chunk == 0) {
    const float* aF = alphag + ((K - 1) & 1) * (BB * RR) + b * RR;
    float part = 0.f;
    for (int s = tid; s < RR; s += 256) part += __expf(aF[s] - A);
#pragma unroll
    for (int off = 32; off > 0; off >>= 1) part += __shfl_xor(part, off);
    if (lane == 0) wred[w][0] = part;
    __syncthreads();
    if (tid == 0) {
      const float se = wred[0][0] + wred[1][0] + wred[2][0] + wred[3][0];
      result[b] = (A + __logf(se)) - dotp;   // fwd - gold
    }
  }
}

// ---------------- Kernel E: final deterministic reduction ----------
__global__ void kE(const float* __restrict__ result, const int* __restrict__ nmen,
                   float* __restrict__ out) {
  if (threadIdx.x == 0 && blockIdx.x == 0) {
    float s = 0.f;
    int d = 0;
    for (int b = 0; b < 32; ++b) { s += result[b]; d += nmen[b]; }
    if (d < 1) d = 1;
    out[0] = s / (float)d;
  }
}

extern "C" void kernel_launch(void* const* d_in, const int* in_sizes, int n_in,
                              void* d_out, int out_size, void* d_ws, size_t ws_size,
                              hipStream_t stream) {
  const float* region = (const float*)d_in[0];
  const float* aff    = (const float*)d_in[1];
  const float* gt     = (const float*)d_in[2];
  const int*   nmen   = (const int*)d_in[3];
  const int*   nreg   = (const int*)d_in[4];
  const float* t0w    = (const float*)d_in[5];
  const float* t0b    = (const float*)d_in[6];
  const float* t1w    = (const float*)d_in[7];
  const float* t1b    = (const float*)d_in[8];
  const float* trw    = (const float*)d_in[9];
  const float* trb    = (const float*)d_in[10];
  float* out = (float*)d_out;
  char* ws = (char*)d_ws;

  size_t off = 0;
  auto alloc = [&](size_t bytes) {
    void* p = ws + off;
    off += (bytes + 255) & ~(size_t)255;
    return p;
  };
  float*    h0h1   = (float*)alloc((size_t)BB * RR * 32 * 4);
  float*    reward = (float*)alloc((size_t)BB * MM * RR * 4);
  float*    rlog   = (float*)alloc((size_t)BB * MM * RR * 4);
  float*    alphag = (float*)alloc((size_t)2 * BB * RR * 4);
  float*    pmaxg  = (float*)alloc((size_t)2 * BB * 8 * 4);
  float*    pdotg  = (float*)alloc((size_t)2 * BB * 8 * 4);
  int*      activ  = (int*)alloc((size_t)BB * MM * 4);
  int*      mlist  = (int*)alloc((size_t)BB * MM * 4);
  int*      kcnt   = (int*)alloc((size_t)BB * 4);
  float*    result = (float*)alloc((size_t)BB * 4);
  unsigned* cnt    = (unsigned*)alloc((size_t)BB * MM * 4);

  hipMemsetAsync(cnt, 0, (size_t)BB * MM * 4, stream);
  kA<<<(BB * RR) / 32, 256, 0, stream>>>(region, t0w, t0b, t1w, t1b, h0h1);
  kC<<<BB * MM, 128, 0, stream>>>(gt, nmen, nreg, reward, rlog, activ);
  kC2<<<1, 64, 0, stream>>>(activ, mlist, kcnt);
  kD<<<256, 256, 0, stream>>>(h0h1, aff, reward, rlog, nreg, mlist, kcnt, trw, trb,
                              alphag, pmaxg, pdotg, cnt, result);
  kE<<<1, 64, 0, stream>>>(result, nmen, out);
}

// Round 2
// 350.618 us; speedup vs baseline: 1.9186x; 1.9186x over previous
//
#include <hip/hip_runtime.h>

#define NEGV (-100000000.0f)

constexpr int BB = 32, MM = 24, RR = 384, DD = 2048;

static __device__ __forceinline__ unsigned f2bf(float x) {  // RNE round to bf16
  union { float f; unsigned u; } v; v.f = x;
  return (v.u + 0x7fffu + ((v.u >> 16) & 1u)) >> 16;
}

// ---------------- Kernel A: h0h1[row][0:16]=region@t0_w^T+t0_b, [16:32]=t1 ----
__global__ __launch_bounds__(256) void kA(const float* __restrict__ region,
    const float* __restrict__ t0w, const float* __restrict__ t0b,
    const float* __restrict__ t1w, const float* __restrict__ t1b,
    float* __restrict__ h0h1) {
  __shared__ float rlds[32][260];
  __shared__ float wlds[256][36];
  const int t = threadIdx.x;
  const int r = t & 31;
  const int q = t >> 5;
  const int row0 = blockIdx.x * 32;
  float acc[32];
#pragma unroll
  for (int h = 0; h < 32; ++h) acc[h] = 0.f;

  for (int tile = 0; tile < 8; ++tile) {
    const int d0 = tile * 256;
    __syncthreads();
#pragma unroll
    for (int i = 0; i < 8; ++i) {
      int flat = i * 256 + t;
      int rr2 = flat >> 6;
      int cc = (flat & 63) << 2;
      *(float4*)&rlds[rr2][cc] =
          *(const float4*)(region + (size_t)(row0 + rr2) * DD + d0 + cc);
    }
#pragma unroll
    for (int h = 0; h < 32; ++h) {
      const float* wsrc = (h < 16) ? (t0w + (size_t)h * DD)
                                   : (t1w + (size_t)(h - 16) * DD);
      wlds[t][h] = wsrc[d0 + t];
    }
    __syncthreads();
    const int djb = q * 32;
#pragma unroll 4
    for (int dj = djb; dj < djb + 32; ++dj) {
      float rv = rlds[r][dj];
      const float4* wp = (const float4*)&wlds[dj][0];
#pragma unroll
      for (int h4 = 0; h4 < 8; ++h4) {
        float4 wv = wp[h4];
        acc[h4 * 4 + 0] = fmaf(rv, wv.x, acc[h4 * 4 + 0]);
        acc[h4 * 4 + 1] = fmaf(rv, wv.y, acc[h4 * 4 + 1]);
        acc[h4 * 4 + 2] = fmaf(rv, wv.z, acc[h4 * 4 + 2]);
        acc[h4 * 4 + 3] = fmaf(rv, wv.w, acc[h4 * 4 + 3]);
      }
    }
  }
  __syncthreads();
  float* red = &wlds[0][0];
#pragma unroll
  for (int h4 = 0; h4 < 8; ++h4) {
    *(float4*)&red[(q * 32 + r) * 36 + h4 * 4] =
        make_float4(acc[h4 * 4 + 0], acc[h4 * 4 + 1], acc[h4 * 4 + 2], acc[h4 * 4 + 3]);
  }
  __syncthreads();
  {
    const int r2 = t & 31;
    const int hb = (t >> 5) * 4;
    float s0 = 0, s1 = 0, s2 = 0, s3 = 0;
#pragma unroll
    for (int qq = 0; qq < 8; ++qq) {
      float4 v = *(const float4*)&red[(qq * 32 + r2) * 36 + hb];
      s0 += v.x; s1 += v.y; s2 += v.z; s3 += v.w;
    }
    float4 bias = (hb < 16) ? *(const float4*)(t0b + hb)
                            : *(const float4*)(t1b + hb - 16);
    *(float4*)(h0h1 + (size_t)(row0 + r2) * 32 + hb) =
        make_float4(s0 + bias.x, s1 + bias.y, s2 + bias.z, s3 + bias.w);
  }
}

// ---------------- Kernel T: tran[b][r][s] in bf16 ----------------
// grid 256 = 32 batches x 8 r-chunks of 48. 256 threads.
__global__ __launch_bounds__(256) void kT(const float* __restrict__ h0h1,
    const float* __restrict__ trw, const float* __restrict__ trb,
    unsigned short* __restrict__ tran) {
  __shared__ float h1T[16][388];
  __shared__ float h0L[48][16];
  const int b = blockIdx.x & 31;
  const int chunk = blockIdx.x >> 5;
  const int r0 = chunk * 48;
  const int tid = threadIdx.x;

  for (int h = 0; h < 16; ++h)
    for (int s = tid; s < RR; s += 256)
      h1T[h][s] = h0h1[((size_t)b * RR + s) * 32 + 16 + h];
  for (int i = tid; i < 768; i += 256) {
    int row = i >> 4, h = i & 15;
    h0L[row][h] = h0h1[((size_t)b * RR + r0 + row) * 32 + h];
  }
  float w0[16];
#pragma unroll
  for (int h = 0; h < 16; ++h) w0[h] = trw[h];
  const float tb = trb[0];
  __syncthreads();

  const int lam = tid & 63;
  const int grp = tid >> 6;      // 4 rows per pass
  const int s0 = lam * 6;
  for (int p = 0; p < 12; ++p) {
    const int row = p * 4 + grp;
    float a0 = tb, a1 = tb, a2 = tb, a3 = tb, a4 = tb, a5 = tb;
#pragma unroll
    for (int h = 0; h < 16; ++h) {
      const float hx = h0L[row][h];
      const float wv = w0[h];
      float2 v0 = *(const float2*)&h1T[h][s0];
      float2 v1 = *(const float2*)&h1T[h][s0 + 2];
      float2 v2 = *(const float2*)&h1T[h][s0 + 4];
      a0 += fmaxf(hx + v0.x, 0.f) * wv;
      a1 += fmaxf(hx + v0.y, 0.f) * wv;
      a2 += fmaxf(hx + v1.x, 0.f) * wv;
      a3 += fmaxf(hx + v1.y, 0.f) * wv;
      a4 += fmaxf(hx + v2.x, 0.f) * wv;
      a5 += fmaxf(hx + v2.y, 0.f) * wv;
    }
    unsigned* outp = (unsigned*)(tran + ((size_t)(b * RR + r0 + row) * RR + s0));
    outp[0] = f2bf(a0) | (f2bf(a1) << 16);
    outp[1] = f2bf(a2) | (f2bf(a3) << 16);
    outp[2] = f2bf(a4) | (f2bf(a5) << 16);
  }
}

// ---------------- Kernel D: the scan. 1 block (1024 thr) per batch ----------
__global__ __launch_bounds__(1024) void kD(
    const unsigned short* __restrict__ tran, const float* __restrict__ aff,
    const float* __restrict__ gt, const int* __restrict__ nmen,
    const int* __restrict__ nreg, float* __restrict__ result) {
  __shared__ float alphaL[RR], scoreL[RR], xAL[RR], eL[RR], laL[RR];
  __shared__ float aBuf[2][RR];
  __shared__ float ared[8], pdred[8];
  __shared__ float wmax[2][16];
  __shared__ float invS[2];
  __shared__ float fred[16], gred[16];
  __shared__ int mlistL[MM];
  __shared__ int Kl;
  __shared__ float sums_pre[MM];

  const int b = blockIdx.x;
  const int tid = threadIdx.x;
  const int w = tid >> 6;
  const int lane = tid & 63;
  const int nr = nreg[b];
  const int nm = nmen[b];

  // ---- prepass: active-mention list ----
  for (int m = w; m < MM; m += 16) {
    float part = 0.f;
#pragma unroll
    for (int i = 0; i < 6; ++i) {
      int s = lane * 6 + i;
      float g = gt[((size_t)(b * MM + m)) * RR + s];
      part += (g >= 0.5f && s < nr && m < nm) ? g : 0.f;
    }
#pragma unroll
    for (int off = 32; off > 0; off >>= 1) part += __shfl_xor(part, off);
    if (lane == 0) sums_pre[m] = part;
  }
  __syncthreads();
  if (tid == 0) {
    int c = 0;
    for (int m = 0; m < MM; ++m)
      if (sums_pre[m] > 0.f) mlistL[c++] = m;
    Kl = c;
  }
  __syncthreads();
  const int K = Kl;
  if (K == 0) {
    if (tid == 0) result[b] = 0.f;
    return;
  }

  const int g = lane >> 4;          // row-in-group 0..3
  const int lam = lane & 15;        // s-chunk owner: s in [lam*24, lam*24+24)
  const unsigned short* tbase = tran + (size_t)b * RR * RR;

  for (int k = 0; k < K; ++k) {
    const int m = mlistL[k];
    const int q = k & 1;

    // ---- phase 2: per-s state (threads 0..383 = waves 0..5) ----
    if (tid < RR) {
      const int s = tid;
      if (k > 0) {
        float Ak = -3.0e38f;
#pragma unroll
        for (int i = 0; i < 16; ++i) Ak = fmaxf(Ak, wmax[q ^ 1][i]);
        xAL[s] = __expf(alphaL[s] - Ak);
      }
      float pd = (k > 0) ? scoreL[s] * aBuf[q ^ 1][s] : 0.f;
      float gv = gt[((size_t)(b * MM + m)) * RR + s];
      float a = (gv >= 0.5f && s < nr) ? gv : 0.f;
      aBuf[q][s] = a;
      laL[s] = (a > 0.f) ? __logf(a) : NEGV;
      eL[s] = aff[((size_t)(b * MM + m)) * RR + s];
      float asA = a;
#pragma unroll
      for (int off = 32; off > 0; off >>= 1) {
        asA += __shfl_xor(asA, off);
        pd += __shfl_xor(pd, off);
      }
      if (lane == 0) { ared[w] = asA; pdred[w] = pd; }
    }
    __syncthreads();  // B1

    // ---- main: all 1024 threads, 6 passes x 4 rows/wave ----
    float stot = 0.f, dotpart = 0.f;
#pragma unroll
    for (int i = 0; i < 6; ++i) { stot += ared[i]; dotpart += pdred[i]; }
    const float inv = 1.f / (stot > 0.f ? stot : 1.f);
    const float lstot = (stot > 0.f) ? __logf(stot) : 0.f;
    float Am = -3.0e38f;
    float invPrev = 0.f, dotS = 0.f;
    if (k > 0) {
#pragma unroll
      for (int i = 0; i < 16; ++i) Am = fmaxf(Am, wmax[q ^ 1][i]);
      invPrev = invS[q ^ 1];
      dotS = dotpart * invPrev;
    }
    float xr[24], rp[24];
    if (k > 0) {
#pragma unroll
      for (int i4 = 0; i4 < 6; ++i4) {
        float4 v = *(const float4*)&xAL[lam * 24 + i4 * 4];
        xr[i4 * 4 + 0] = v.x; xr[i4 * 4 + 1] = v.y;
        xr[i4 * 4 + 2] = v.z; xr[i4 * 4 + 3] = v.w;
        float4 u = *(const float4*)&aBuf[q ^ 1][lam * 24 + i4 * 4];
        rp[i4 * 4 + 0] = u.x; rp[i4 * 4 + 1] = u.y;
        rp[i4 * 4 + 2] = u.z; rp[i4 * 4 + 3] = u.w;
      }
    }
    float lmax = -3.0e38f;
#pragma unroll 1
    for (int p = 0; p < 6; ++p) {
      const int row = w * 24 + p * 4 + g;
      float asum = 0.f, tsum = 0.f;
      if (k > 0) {
        const uint4* tp = (const uint4*)(tbase + (size_t)row * RR + lam * 24);
        uint4 u0 = tp[0], u1 = tp[1], u2 = tp[2];
        unsigned dw[12] = {u0.x, u0.y, u0.z, u0.w, u1.x, u1.y, u1.z, u1.w,
                           u2.x, u2.y, u2.z, u2.w};
#pragma unroll
        for (int j = 0; j < 12; ++j) {
          float tl = __uint_as_float(dw[j] << 16);
          float th = __uint_as_float(dw[j] & 0xffff0000u);
          asum = fmaf(__expf(tl), xr[2 * j], asum);
          tsum = fmaf(tl, rp[2 * j], tsum);
          asum = fmaf(__expf(th), xr[2 * j + 1], asum);
          tsum = fmaf(th, rp[2 * j + 1], tsum);
        }
#pragma unroll
        for (int off = 1; off < 16; off <<= 1) {
          asum += __shfl_xor(asum, off);
          tsum += __shfl_xor(tsum, off);
        }
      }
      const float e = eL[row];
      const float rl = laL[row] - lstot;
      float an, sn;
      if (k == 0) {
        an = ((row < nr) ? 0.f : NEGV) + e;
        sn = e - rl;
      } else {
        an = Am + __logf(asum) + e;
        sn = dotS + tsum * invPrev + e - rl;
      }
      lmax = fmaxf(lmax, an);
      if (lam == 0) { alphaL[row] = an; scoreL[row] = sn; }
    }
#pragma unroll
    for (int off = 32; off > 0; off >>= 1) lmax = fmaxf(lmax, __shfl_xor(lmax, off));
    if (lane == 0) wmax[q][w] = lmax;
    if (tid == 0) invS[q] = inv;
    __syncthreads();  // B0 (top of next step)
  }

  // ---- epilogue ----
  const int qf = (K - 1) & 1;
  float Af = -3.0e38f;
#pragma unroll
  for (int i = 0; i < 16; ++i) Af = fmaxf(Af, wmax[qf][i]);
  float fpart = 0.f, gpart = 0.f;
  if (tid < RR) {
    fpart = __expf(alphaL[tid] - Af);
    gpart = scoreL[tid] * aBuf[qf][tid];
  }
#pragma unroll
  for (int off = 32; off > 0; off >>= 1) {
    fpart += __shfl_xor(fpart, off);
    gpart += __shfl_xor(gpart, off);
  }
  if (lane == 0) { fred[w] = fpart; gred[w] = gpart; }
  __syncthreads();
  if (tid == 0) {
    float fs = 0.f, gs = 0.f;
#pragma unroll
    for (int i = 0; i < 16; ++i) { fs += fred[i]; gs += gred[i]; }
    const float fwd = Af + __logf(fs);
    const float gold = gs * invS[qf];
    result[b] = fwd - gold;
  }
}

// ---------------- Kernel E: final deterministic reduction ----------
__global__ void kE(const float* __restrict__ result, const int* __restrict__ nmen,
                   float* __restrict__ out) {
  if (threadIdx.x == 0 && blockIdx.x == 0) {
    float s = 0.f;
    int d = 0;
    for (int b = 0; b < 32; ++b) { s += result[b]; d += nmen[b]; }
    if (d < 1) d = 1;
    out[0] = s / (float)d;
  }
}

extern "C" void kernel_launch(void* const* d_in, const int* in_sizes, int n_in,
                              void* d_out, int out_size, void* d_ws, size_t ws_size,
                              hipStream_t stream) {
  const float* region = (const float*)d_in[0];
  const float* aff    = (const float*)d_in[1];
  const float* gt     = (const float*)d_in[2];
  const int*   nmen   = (const int*)d_in[3];
  const int*   nreg   = (const int*)d_in[4];
  const float* t0w    = (const float*)d_in[5];
  const float* t0b    = (const float*)d_in[6];
  const float* t1w    = (const float*)d_in[7];
  const float* t1b    = (const float*)d_in[8];
  const float* trw    = (const float*)d_in[9];
  const float* trb    = (const float*)d_in[10];
  float* out = (float*)d_out;
  char* ws = (char*)d_ws;

  size_t off = 0;
  auto alloc = [&](size_t bytes) {
    void* p = ws + off;
    off += (bytes + 255) & ~(size_t)255;
    return p;
  };
  float*          h0h1   = (float*)alloc((size_t)BB * RR * 32 * 4);
  unsigned short* tranb  = (unsigned short*)alloc((size_t)BB * RR * RR * 2);
  float*          result = (float*)alloc((size_t)BB * 4);

  kA<<<(BB * RR) / 32, 256, 0, stream>>>(region, t0w, t0b, t1w, t1b, h0h1);
  kT<<<256, 256, 0, stream>>>(h0h1, trw, trb, tranb);
  kD<<<BB, 1024, 0, stream>>>(tranb, aff, gt, nmen, nreg, result);
  kE<<<1, 64, 0, stream>>>(result, nmen, out);
}

// Round 4
// 239.792 us; speedup vs baseline: 2.8053x; 1.4622x over previous
//
#include <hip/hip_runtime.h>

#define NEGV (-100000000.0f)

constexpr int BB = 32, MM = 24, RR = 384, DD = 2048;

static __device__ __forceinline__ unsigned f2bf(float x) {  // RNE round to bf16
  union { float f; unsigned u; } v; v.f = x;
  return (v.u + 0x7fffu + ((v.u >> 16) & 1u)) >> 16;
}

// ---------------- Kernel A: h0h1[row][0:16]=region@t0_w^T+t0_b, [16:32]=t1 ----
// (round-2 proven version)
__global__ __launch_bounds__(256) void kA(const float* __restrict__ region,
    const float* __restrict__ t0w, const float* __restrict__ t0b,
    const float* __restrict__ t1w, const float* __restrict__ t1b,
    float* __restrict__ h0h1) {
  __shared__ float rlds[32][260];
  __shared__ float wlds[256][36];
  const int t = threadIdx.x;
  const int r = t & 31;
  const int q = t >> 5;
  const int row0 = blockIdx.x * 32;
  float acc[32];
#pragma unroll
  for (int h = 0; h < 32; ++h) acc[h] = 0.f;

  for (int tile = 0; tile < 8; ++tile) {
    const int d0 = tile * 256;
    __syncthreads();
#pragma unroll
    for (int i = 0; i < 8; ++i) {
      int flat = i * 256 + t;
      int rr2 = flat >> 6;
      int cc = (flat & 63) << 2;
      *(float4*)&rlds[rr2][cc] =
          *(const float4*)(region + (size_t)(row0 + rr2) * DD + d0 + cc);
    }
#pragma unroll
    for (int h = 0; h < 32; ++h) {
      const float* wsrc = (h < 16) ? (t0w + (size_t)h * DD)
                                   : (t1w + (size_t)(h - 16) * DD);
      wlds[t][h] = wsrc[d0 + t];
    }
    __syncthreads();
    const int djb = q * 32;
#pragma unroll 4
    for (int dj = djb; dj < djb + 32; ++dj) {
      float rv = rlds[r][dj];
      const float4* wp = (const float4*)&wlds[dj][0];
#pragma unroll
      for (int h4 = 0; h4 < 8; ++h4) {
        float4 wv = wp[h4];
        acc[h4 * 4 + 0] = fmaf(rv, wv.x, acc[h4 * 4 + 0]);
        acc[h4 * 4 + 1] = fmaf(rv, wv.y, acc[h4 * 4 + 1]);
        acc[h4 * 4 + 2] = fmaf(rv, wv.z, acc[h4 * 4 + 2]);
        acc[h4 * 4 + 3] = fmaf(rv, wv.w, acc[h4 * 4 + 3]);
      }
    }
  }
  __syncthreads();
  float* red = &wlds[0][0];
#pragma unroll
  for (int h4 = 0; h4 < 8; ++h4) {
    *(float4*)&red[(q * 32 + r) * 36 + h4 * 4] =
        make_float4(acc[h4 * 4 + 0], acc[h4 * 4 + 1], acc[h4 * 4 + 2], acc[h4 * 4 + 3]);
  }
  __syncthreads();
  {
    const int r2 = t & 31;
    const int hb = (t >> 5) * 4;
    float s0 = 0, s1 = 0, s2 = 0, s3 = 0;
#pragma unroll
    for (int qq = 0; qq < 8; ++qq) {
      float4 v = *(const float4*)&red[(qq * 32 + r2) * 36 + hb];
      s0 += v.x; s1 += v.y; s2 += v.z; s3 += v.w;
    }
    float4 bias = (hb < 16) ? *(const float4*)(t0b + hb)
                            : *(const float4*)(t1b + hb - 16);
    *(float4*)(h0h1 + (size_t)(row0 + r2) * 32 + hb) =
        make_float4(s0 + bias.x, s1 + bias.y, s2 + bias.z, s3 + bias.w);
  }
}

// ---------------- Kernel T: expb[b][r][s] = exp(tran) in bf16 ----------------
__global__ __launch_bounds__(256) void kT(const float* __restrict__ h0h1,
    const float* __restrict__ trw, const float* __restrict__ trb,
    unsigned short* __restrict__ expb) {
  __shared__ float h1T[16][388];
  __shared__ float h0L[48][16];
  const int b = blockIdx.x & 31;
  const int chunk = blockIdx.x >> 5;
  const int r0 = chunk * 48;
  const int tid = threadIdx.x;

  for (int h = 0; h < 16; ++h)
    for (int s = tid; s < RR; s += 256)
      h1T[h][s] = h0h1[((size_t)b * RR + s) * 32 + 16 + h];
  for (int i = tid; i < 768; i += 256) {
    int row = i >> 4, h = i & 15;
    h0L[row][h] = h0h1[((size_t)b * RR + r0 + row) * 32 + h];
  }
  float w0[16];
#pragma unroll
  for (int h = 0; h < 16; ++h) w0[h] = trw[h];
  const float tb = trb[0];
  __syncthreads();

  const int lam = tid & 63;
  const int grp = tid >> 6;
  const int s0 = lam * 6;
  for (int p = 0; p < 12; ++p) {
    const int row = p * 4 + grp;
    float a0 = tb, a1 = tb, a2 = tb, a3 = tb, a4 = tb, a5 = tb;
#pragma unroll
    for (int h = 0; h < 16; ++h) {
      const float hx = h0L[row][h];
      const float wv = w0[h];
      float2 v0 = *(const float2*)&h1T[h][s0];
      float2 v1 = *(const float2*)&h1T[h][s0 + 2];
      float2 v2 = *(const float2*)&h1T[h][s0 + 4];
      a0 += fmaxf(hx + v0.x, 0.f) * wv;
      a1 += fmaxf(hx + v0.y, 0.f) * wv;
      a2 += fmaxf(hx + v1.x, 0.f) * wv;
      a3 += fmaxf(hx + v1.y, 0.f) * wv;
      a4 += fmaxf(hx + v2.x, 0.f) * wv;
      a5 += fmaxf(hx + v2.y, 0.f) * wv;
    }
    const size_t base = (size_t)(b * RR + r0 + row) * RR + s0;
    unsigned* oe = (unsigned*)(expb + base);
    oe[0] = f2bf(__expf(fminf(a0, 80.f))) | (f2bf(__expf(fminf(a1, 80.f))) << 16);
    oe[1] = f2bf(__expf(fminf(a2, 80.f))) | (f2bf(__expf(fminf(a3, 80.f))) << 16);
    oe[2] = f2bf(__expf(fminf(a4, 80.f))) | (f2bf(__expf(fminf(a5, 80.f))) << 16);
  }
}

// ---------------- Kernel CM: row sums + compact active-m list ---------------
__global__ __launch_bounds__(64) void kCM(const float* __restrict__ gt,
    const int* __restrict__ nmen, const int* __restrict__ nreg,
    float* __restrict__ rsum, int* __restrict__ mlist, int* __restrict__ kcnt) {
  const int b = blockIdx.x;
  const int lane = threadIdx.x;
  const int nm = nmen[b], nr = nreg[b];
  int c = 0;
  for (int m = 0; m < MM; ++m) {
    float p = 0.f;
#pragma unroll
    for (int i = 0; i < 6; ++i) {
      int s = lane * 6 + i;
      float g = gt[((size_t)(b * MM + m)) * RR + s];
      p += (g >= 0.5f && s < nr && m < nm) ? g : 0.f;
    }
#pragma unroll
    for (int off = 32; off > 0; off >>= 1) p += __shfl_xor(p, off);
    if (lane == 0) {
      rsum[b * MM + m] = p;
      if (p > 0.f) mlist[b * MM + (c++)] = m;
    }
  }
  if (lane == 0) {
    kcnt[b] = c;
    for (int j = c; j < MM; ++j) mlist[b * MM + j] = 0;
  }
}

// ---------------- Kernel E2: Em[b][m] = sum rp*(e - log rp) -----------------
__global__ __launch_bounds__(128) void kE2(const float* __restrict__ gt,
    const float* __restrict__ aff, const int* __restrict__ nmen,
    const int* __restrict__ nreg, float* __restrict__ Em) {
  const int bm = blockIdx.x;
  const int b = bm / MM, m = bm - b * MM;
  const int t = threadIdx.x;
  const int nm = nmen[b], nr = nreg[b];
  float t1 = 0.f, t2 = 0.f, ss = 0.f;
#pragma unroll
  for (int i = 0; i < 3; ++i) {
    int s = t + i * 128;
    float g = gt[(size_t)bm * RR + s];
    float a = (g >= 0.5f && s < nr && m < nm) ? g : 0.f;
    float e = aff[(size_t)bm * RR + s];
    t1 += a * e;
    ss += a;
    t2 += (a > 0.f) ? a * __logf(a) : 0.f;
  }
#pragma unroll
  for (int off = 32; off > 0; off >>= 1) {
    t1 += __shfl_xor(t1, off);
    t2 += __shfl_xor(t2, off);
    ss += __shfl_xor(ss, off);
  }
  __shared__ float r1[2], r2[2], r3[2];
  if ((t & 63) == 0) { r1[t >> 6] = t1; r2[t >> 6] = t2; r3[t >> 6] = ss; }
  __syncthreads();
  if (t == 0) {
    float T1 = r1[0] + r1[1], T2 = r2[0] + r2[1], S = r3[0] + r3[1];
    Em[bm] = (S > 0.f) ? (T1 - T2) / S + __logf(S) : 0.f;
  }
}

// ---------------- Kernel Y: bilinP[b][chunk][j] = partial rp_j^T T rp_{j-1} --
// Computes its own fp32 tran tile from h0h1 (no global tran buffer needed).
// grid 256 = (b x 8 chunks of 48 rows), 192 threads = (48 rows x 4 jq of 6 j).
__global__ __launch_bounds__(192) void kY(const float* __restrict__ h0h1,
    const float* __restrict__ trw, const float* __restrict__ trb,
    const float* __restrict__ gt, const int* __restrict__ nreg,
    const float* __restrict__ rsum, const int* __restrict__ mlist,
    const int* __restrict__ kcnt, float* __restrict__ bilinP) {
  __shared__ float h1T[16][388];
  __shared__ float h0L[48][16];
  __shared__ float Tl[48][388];
  __shared__ float RP[MM][392];
  __shared__ float part[48][26];
  const int b = blockIdx.x & 31;
  const int chunk = blockIdx.x >> 5;
  const int r0 = chunk * 48;
  const int tid = threadIdx.x;
  const int K = kcnt[b];
  const int nr = nreg[b];

  for (int h = 0; h < 16; ++h)
    for (int s = tid; s < RR; s += 192)
      h1T[h][s] = h0h1[((size_t)b * RR + s) * 32 + 16 + h];
  for (int i = tid; i < 768; i += 192) {
    int row = i >> 4, h = i & 15;
    h0L[row][h] = h0h1[((size_t)b * RR + r0 + row) * 32 + h];
  }
  for (int j = 0; j < MM; ++j) {
    if (j < K) {
      int m = mlist[b * MM + j];
      float inv = 1.f / rsum[b * MM + m];
      for (int s = tid; s < RR; s += 192) {
        float g = gt[((size_t)(b * MM + m)) * RR + s];
        RP[j][s] = (g >= 0.5f && s < nr) ? g * inv : 0.f;
      }
    } else {
      for (int s = tid; s < RR; s += 192) RP[j][s] = 0.f;
    }
  }
  float w0[16];
#pragma unroll
  for (int h = 0; h < 16; ++h) w0[h] = trw[h];
  const float tb = trb[0];
  __syncthreads();

  const int r = tid >> 2;
  const int jq = tid & 3;

  // compute my tran rows (fp32): thread (r,jq) owns s in [jq*96, jq*96+96)
  for (int s = jq * 96; s < jq * 96 + 96; ++s) {
    float a = tb;
#pragma unroll
    for (int h = 0; h < 16; ++h)
      a += fmaxf(h0L[r][h] + h1T[h][s], 0.f) * w0[h];
    Tl[r][s] = a;
  }
  __syncthreads();

  float acc[6] = {0, 0, 0, 0, 0, 0};
  for (int s0 = 0; s0 < RR; s0 += 4) {
    float4 tv = *(const float4*)&Tl[r][s0];
#pragma unroll
    for (int jj = 0; jj < 6; ++jj) {
      const float4 p0 = *(const float4*)&RP[jq * 6 + jj][s0];
      acc[jj] = fmaf(tv.x, p0.x, acc[jj]);
      acc[jj] = fmaf(tv.y, p0.y, acc[jj]);
      acc[jj] = fmaf(tv.z, p0.z, acc[jj]);
      acc[jj] = fmaf(tv.w, p0.w, acc[jj]);
    }
  }
  const int gr = chunk * 48 + r;
#pragma unroll
  for (int jj = 0; jj < 6; ++jj) {
    const int jp = jq * 6 + jj;          // acc[jj] = (T rp_jp)[gr]
    const int j = jp + 1;                // contributes to bilin_j
    part[r][j] = (j < K) ? RP[j][gr] * acc[jj] : 0.f;
  }
  __syncthreads();
  if (tid < MM) {
    const int j = tid;
    float s = 0.f;
    if (j >= 1) {
#pragma unroll 4
      for (int rr2 = 0; rr2 < 48; ++rr2) s += part[rr2][j];
    }
    bilinP[(size_t)(b * 8 + chunk) * MM + j] = s;
  }
}

// ---------------- Kernel D: alpha-only scan. 1 block (1024 thr) per batch ----
__global__ __launch_bounds__(1024) void kD(
    const unsigned short* __restrict__ expb, const float* __restrict__ aff,
    const int* __restrict__ nreg, const int* __restrict__ mlist,
    const int* __restrict__ kcnt, const float* __restrict__ Em,
    const float* __restrict__ bilinP, float* __restrict__ result) {
  __shared__ unsigned short eHi[192 * RR];     // expT rows 192..383 (147456 B)
  __shared__ float alphaL[2][RR];
  __shared__ float wmax[2][16];
  __shared__ float fred[16];

  const int b = blockIdx.x;
  const int tid = threadIdx.x;
  const int w = tid >> 6;
  const int lane = tid & 63;
  const int lam = lane & 15;
  const int g = lane >> 4;
  const int nr = nreg[b];
  const unsigned short* ebase = expb + (size_t)b * RR * RR;

  const int K = kcnt[b];
  if (K == 0) {
    if (tid == 0) result[b] = 0.f;
    return;
  }
  {  // stage rows 192..383 into LDS (visible by the k=0 end-of-step barrier)
    const uint4* src = (const uint4*)(ebase + 192 * RR);
    uint4* dst = (uint4*)eHi;
    for (int i = tid; i < 192 * RR / 8; i += 1024) dst[i] = src[i];
  }

  const int myrow0 = w * 24;
  const bool hi = (w >= 8);

  for (int k = 0; k < K; ++k) {
    const int q = k & 1;
    const int m = mlist[b * MM + k];
    const float* arow = aff + ((size_t)(b * MM + m)) * RR;
    float lmax = -3.0e38f;
    if (k == 0) {
#pragma unroll
      for (int p = 0; p < 6; ++p) {
        const int row = myrow0 + p * 4 + g;
        float an = ((row < nr) ? 0.f : NEGV) + arow[row];
        lmax = fmaxf(lmax, an);
        if (lam == 0) alphaL[q][row] = an;
      }
    } else {
      float Ak = -3.0e38f;
#pragma unroll
      for (int i = 0; i < 16; ++i) Ak = fmaxf(Ak, wmax[q ^ 1][i]);
      float xr[24];
#pragma unroll
      for (int j = 0; j < 24; ++j)
        xr[j] = __expf(alphaL[q ^ 1][lam * 24 + j] - Ak);
      float eP[6];
#pragma unroll
      for (int p = 0; p < 6; ++p) eP[p] = arow[myrow0 + p * 4 + g];
      uint4 c0, c1, c2, n0, n1, n2;
      auto LD = [&](int p, uint4& A, uint4& B, uint4& C) {
        const int row = myrow0 + p * 4 + g;
        if (hi) {
          const uint4* lp = (const uint4*)&eHi[(row - 192) * RR + lam * 24];
          A = lp[0]; B = lp[1]; C = lp[2];
        } else {
          const uint4* gp = (const uint4*)(ebase + ((size_t)row * RR + lam * 24));
          A = gp[0]; B = gp[1]; C = gp[2];
        }
      };
      LD(0, c0, c1, c2);
#pragma unroll
      for (int p = 0; p < 6; ++p) {
        if (p < 5) LD(p + 1, n0, n1, n2);
        const unsigned dw[12] = {c0.x, c0.y, c0.z, c0.w, c1.x, c1.y, c1.z, c1.w,
                                 c2.x, c2.y, c2.z, c2.w};
        float ax = 0.f, ay = 0.f;
#pragma unroll
        for (int j = 0; j < 12; ++j) {
          ax = fmaf(__uint_as_float(dw[j] << 16), xr[2 * j], ax);
          ay = fmaf(__uint_as_float(dw[j] & 0xffff0000u), xr[2 * j + 1], ay);
        }
        float asum = ax + ay;
#pragma unroll
        for (int off = 1; off < 16; off <<= 1) asum += __shfl_xor(asum, off);
        const float an = Ak + __logf(fmaxf(asum, 1e-37f)) + eP[p];
        lmax = fmaxf(lmax, an);
        if (lam == 0) alphaL[q][myrow0 + p * 4 + g] = an;
        c0 = n0; c1 = n1; c2 = n2;
      }
    }
#pragma unroll
    for (int off = 32; off > 0; off >>= 1) lmax = fmaxf(lmax, __shfl_xor(lmax, off));
    if (lane == 0) wmax[q][w] = lmax;
    __syncthreads();
  }

  // epilogue: fwd = logsumexp(alpha); gold from precomputed bilin/Em
  const int qf = (K - 1) & 1;
  float Af = -3.0e38f;
#pragma unroll
  for (int i = 0; i < 16; ++i) Af = fmaxf(Af, wmax[qf][i]);
  float fp = (tid < RR) ? __expf(alphaL[qf][tid] - Af) : 0.f;
#pragma unroll
  for (int off = 32; off > 0; off >>= 1) fp += __shfl_xor(fp, off);
  if (lane == 0) fred[w] = fp;
  __syncthreads();
  if (tid == 0) {
    float fs = 0.f;
#pragma unroll
    for (int i = 0; i < 16; ++i) fs += fred[i];
    float gold = Em[b * MM + mlist[b * MM + 0]];
    for (int j = 1; j < K; ++j) {
      float bil = 0.f;
#pragma unroll
      for (int c = 0; c < 8; ++c) bil += bilinP[(size_t)(b * 8 + c) * MM + j];
      gold += bil + Em[b * MM + mlist[b * MM + j]];
    }
    result[b] = (Af + __logf(fs)) - gold;
  }
}

// ---------------- Kernel E: final deterministic reduction ----------
__global__ void kE(const float* __restrict__ result, const int* __restrict__ nmen,
                   float* __restrict__ out) {
  if (threadIdx.x == 0 && blockIdx.x == 0) {
    float s = 0.f;
    int d = 0;
    for (int b = 0; b < 32; ++b) { s += result[b]; d += nmen[b]; }
    if (d < 1) d = 1;
    out[0] = s / (float)d;
  }
}

extern "C" void kernel_launch(void* const* d_in, const int* in_sizes, int n_in,
                              void* d_out, int out_size, void* d_ws, size_t ws_size,
                              hipStream_t stream) {
  const float* region = (const float*)d_in[0];
  const float* aff    = (const float*)d_in[1];
  const float* gt     = (const float*)d_in[2];
  const int*   nmen   = (const int*)d_in[3];
  const int*   nreg   = (const int*)d_in[4];
  const float* t0w    = (const float*)d_in[5];
  const float* t0b    = (const float*)d_in[6];
  const float* t1w    = (const float*)d_in[7];
  const float* t1b    = (const float*)d_in[8];
  const float* trw    = (const float*)d_in[9];
  const float* trb    = (const float*)d_in[10];
  float* out = (float*)d_out;
  char* ws = (char*)d_ws;

  size_t off = 0;
  auto alloc = [&](size_t bytes) {
    void* p = ws + off;
    off += (bytes + 255) & ~(size_t)255;
    return p;
  };
  float*          h0h1   = (float*)alloc((size_t)BB * RR * 32 * 4);   // 1.57 MB
  unsigned short* expb   = (unsigned short*)alloc((size_t)BB * RR * RR * 2); // 9.44 MB
  float*          rsum   = (float*)alloc((size_t)BB * MM * 4);
  int*            mlist  = (int*)alloc((size_t)BB * MM * 4);
  int*            kcnt   = (int*)alloc((size_t)BB * 4);
  float*          Em     = (float*)alloc((size_t)BB * MM * 4);
  float*          bilinP = (float*)alloc((size_t)BB * 8 * MM * 4);
  float*          result = (float*)alloc((size_t)BB * 4);

  kA<<<(BB * RR) / 32, 256, 0, stream>>>(region, t0w, t0b, t1w, t1b, h0h1);
  kCM<<<BB, 64, 0, stream>>>(gt, nmen, nreg, rsum, mlist, kcnt);
  kT<<<256, 256, 0, stream>>>(h0h1, trw, trb, expb);
  kE2<<<BB * MM, 128, 0, stream>>>(gt, aff, nmen, nreg, Em);
  kY<<<256, 192, 0, stream>>>(h0h1, trw, trb, gt, nreg, rsum, mlist, kcnt, bilinP);
  kD<<<BB, 1024, 0, stream>>>(expb, aff, nreg, mlist, kcnt, Em, bilinP, result);
  kE<<<1, 64, 0, stream>>>(result, nmen, out);
}

// Round 5
// 224.434 us; speedup vs baseline: 2.9973x; 1.0684x over previous
//
#include <hip/hip_runtime.h>

#define NEGV (-100000000.0f)

constexpr int BB = 32, MM = 24, RR = 384, DD = 2048;

static __device__ __forceinline__ unsigned f2bf(float x) {  // RNE round to bf16
  union { float f; unsigned u; } v; v.f = x;
  return (v.u + 0x7fffu + ((v.u >> 16) & 1u)) >> 16;
}

// ---------------- Kernel A: h0h1[row][0:16]=region@t0_w^T+t0_b, [16:32]=t1 ----
__global__ __launch_bounds__(256) void kA(const float* __restrict__ region,
    const float* __restrict__ t0w, const float* __restrict__ t0b,
    const float* __restrict__ t1w, const float* __restrict__ t1b,
    float* __restrict__ h0h1) {
  __shared__ float rlds[32][260];
  __shared__ float wlds[256][36];
  const int t = threadIdx.x;
  const int r = t & 31;
  const int q = t >> 5;
  const int row0 = blockIdx.x * 32;
  float acc[32];
#pragma unroll
  for (int h = 0; h < 32; ++h) acc[h] = 0.f;

  for (int tile = 0; tile < 8; ++tile) {
    const int d0 = tile * 256;
    __syncthreads();
#pragma unroll
    for (int i = 0; i < 8; ++i) {
      int flat = i * 256 + t;
      int rr2 = flat >> 6;
      int cc = (flat & 63) << 2;
      *(float4*)&rlds[rr2][cc] =
          *(const float4*)(region + (size_t)(row0 + rr2) * DD + d0 + cc);
    }
#pragma unroll
    for (int h = 0; h < 32; ++h) {
      const float* wsrc = (h < 16) ? (t0w + (size_t)h * DD)
                                   : (t1w + (size_t)(h - 16) * DD);
      wlds[t][h] = wsrc[d0 + t];
    }
    __syncthreads();
    const int djb = q * 32;
#pragma unroll 4
    for (int dj = djb; dj < djb + 32; ++dj) {
      float rv = rlds[r][dj];
      const float4* wp = (const float4*)&wlds[dj][0];
#pragma unroll
      for (int h4 = 0; h4 < 8; ++h4) {
        float4 wv = wp[h4];
        acc[h4 * 4 + 0] = fmaf(rv, wv.x, acc[h4 * 4 + 0]);
        acc[h4 * 4 + 1] = fmaf(rv, wv.y, acc[h4 * 4 + 1]);
        acc[h4 * 4 + 2] = fmaf(rv, wv.z, acc[h4 * 4 + 2]);
        acc[h4 * 4 + 3] = fmaf(rv, wv.w, acc[h4 * 4 + 3]);
      }
    }
  }
  __syncthreads();
  float* red = &wlds[0][0];
#pragma unroll
  for (int h4 = 0; h4 < 8; ++h4) {
    *(float4*)&red[(q * 32 + r) * 36 + h4 * 4] =
        make_float4(acc[h4 * 4 + 0], acc[h4 * 4 + 1], acc[h4 * 4 + 2], acc[h4 * 4 + 3]);
  }
  __syncthreads();
  {
    const int r2 = t & 31;
    const int hb = (t >> 5) * 4;
    float s0 = 0, s1 = 0, s2 = 0, s3 = 0;
#pragma unroll
    for (int qq = 0; qq < 8; ++qq) {
      float4 v = *(const float4*)&red[(qq * 32 + r2) * 36 + hb];
      s0 += v.x; s1 += v.y; s2 += v.z; s3 += v.w;
    }
    float4 bias = (hb < 16) ? *(const float4*)(t0b + hb)
                            : *(const float4*)(t1b + hb - 16);
    *(float4*)(h0h1 + (size_t)(row0 + r2) * 32 + hb) =
        make_float4(s0 + bias.x, s1 + bias.y, s2 + bias.z, s3 + bias.w);
  }
}

// ---------------- Kernel T: expb[b][r][s] = exp(tran) in bf16 ----------------
__global__ __launch_bounds__(256) void kT(const float* __restrict__ h0h1,
    const float* __restrict__ trw, const float* __restrict__ trb,
    unsigned short* __restrict__ expb) {
  __shared__ float h1T[16][388];
  __shared__ float h0L[48][16];
  const int b = blockIdx.x & 31;
  const int chunk = blockIdx.x >> 5;
  const int r0 = chunk * 48;
  const int tid = threadIdx.x;

  for (int h = 0; h < 16; ++h)
    for (int s = tid; s < RR; s += 256)
      h1T[h][s] = h0h1[((size_t)b * RR + s) * 32 + 16 + h];
  for (int i = tid; i < 768; i += 256) {
    int row = i >> 4, h = i & 15;
    h0L[row][h] = h0h1[((size_t)b * RR + r0 + row) * 32 + h];
  }
  float w0[16];
#pragma unroll
  for (int h = 0; h < 16; ++h) w0[h] = trw[h];
  const float tb = trb[0];
  __syncthreads();

  const int lam = tid & 63;
  const int grp = tid >> 6;
  const int s0 = lam * 6;
  for (int p = 0; p < 12; ++p) {
    const int row = p * 4 + grp;
    float a0 = tb, a1 = tb, a2 = tb, a3 = tb, a4 = tb, a5 = tb;
#pragma unroll
    for (int h = 0; h < 16; ++h) {
      const float hx = h0L[row][h];
      const float wv = w0[h];
      float2 v0 = *(const float2*)&h1T[h][s0];
      float2 v1 = *(const float2*)&h1T[h][s0 + 2];
      float2 v2 = *(const float2*)&h1T[h][s0 + 4];
      a0 += fmaxf(hx + v0.x, 0.f) * wv;
      a1 += fmaxf(hx + v0.y, 0.f) * wv;
      a2 += fmaxf(hx + v1.x, 0.f) * wv;
      a3 += fmaxf(hx + v1.y, 0.f) * wv;
      a4 += fmaxf(hx + v2.x, 0.f) * wv;
      a5 += fmaxf(hx + v2.y, 0.f) * wv;
    }
    const size_t base = (size_t)(b * RR + r0 + row) * RR + s0;
    unsigned* oe = (unsigned*)(expb + base);
    oe[0] = f2bf(__expf(fminf(a0, 80.f))) | (f2bf(__expf(fminf(a1, 80.f))) << 16);
    oe[1] = f2bf(__expf(fminf(a2, 80.f))) | (f2bf(__expf(fminf(a3, 80.f))) << 16);
    oe[2] = f2bf(__expf(fminf(a4, 80.f))) | (f2bf(__expf(fminf(a5, 80.f))) << 16);
  }
}

// ---------------- Kernel CM: rsum + Em + compact active-m list (merged) -----
__global__ __launch_bounds__(64) void kCM(const float* __restrict__ gt,
    const float* __restrict__ aff, const int* __restrict__ nmen,
    const int* __restrict__ nreg, float* __restrict__ rsum,
    float* __restrict__ Em, int* __restrict__ mlist, int* __restrict__ kcnt) {
  const int b = blockIdx.x;
  const int lane = threadIdx.x;
  const int nm = nmen[b], nr = nreg[b];
  int c = 0;
  for (int m = 0; m < MM; ++m) {
    const size_t bm = (size_t)(b * MM + m);
    float p = 0.f, t1 = 0.f, t2 = 0.f;
#pragma unroll
    for (int i = 0; i < 6; ++i) {
      int s = lane * 6 + i;
      float g = gt[bm * RR + s];
      float a = (g >= 0.5f && s < nr && m < nm) ? g : 0.f;
      float e = aff[bm * RR + s];
      p += a;
      t1 += a * e;
      t2 += (a > 0.f) ? a * __logf(a) : 0.f;
    }
#pragma unroll
    for (int off = 32; off > 0; off >>= 1) {
      p += __shfl_xor(p, off);
      t1 += __shfl_xor(t1, off);
      t2 += __shfl_xor(t2, off);
    }
    if (lane == 0) {
      rsum[bm] = p;
      Em[bm] = (p > 0.f) ? (t1 - t2) / p + __logf(p) : 0.f;
      if (p > 0.f) mlist[b * MM + (c++)] = m;
    }
  }
  if (lane == 0) {
    kcnt[b] = c;
    for (int j = c; j < MM; ++j) mlist[b * MM + j] = 0;
  }
}

// ---------------- Kernel Y: bilinP[b][chunk][j] = partial rp_j^T T rp_{j-1} --
__global__ __launch_bounds__(192) void kY(const float* __restrict__ h0h1,
    const float* __restrict__ trw, const float* __restrict__ trb,
    const float* __restrict__ gt, const int* __restrict__ nreg,
    const float* __restrict__ rsum, const int* __restrict__ mlist,
    const int* __restrict__ kcnt, float* __restrict__ bilinP) {
  __shared__ float h1T[16][388];
  __shared__ float h0L[48][16];
  __shared__ float Tl[48][388];
  __shared__ float RP[MM][392];
  __shared__ float part[48][26];
  const int b = blockIdx.x & 31;
  const int chunk = blockIdx.x >> 5;
  const int r0 = chunk * 48;
  const int tid = threadIdx.x;
  const int K = kcnt[b];
  const int nr = nreg[b];

  for (int h = 0; h < 16; ++h)
    for (int s = tid; s < RR; s += 192)
      h1T[h][s] = h0h1[((size_t)b * RR + s) * 32 + 16 + h];
  for (int i = tid; i < 768; i += 192) {
    int row = i >> 4, h = i & 15;
    h0L[row][h] = h0h1[((size_t)b * RR + r0 + row) * 32 + h];
  }
  for (int j = 0; j < MM; ++j) {
    if (j < K) {
      int m = mlist[b * MM + j];
      float inv = 1.f / rsum[b * MM + m];
      for (int s = tid; s < RR; s += 192) {
        float g = gt[((size_t)(b * MM + m)) * RR + s];
        RP[j][s] = (g >= 0.5f && s < nr) ? g * inv : 0.f;
      }
    } else {
      for (int s = tid; s < RR; s += 192) RP[j][s] = 0.f;
    }
  }
  float w0[16];
#pragma unroll
  for (int h = 0; h < 16; ++h) w0[h] = trw[h];
  const float tb = trb[0];
  __syncthreads();

  const int r = tid >> 2;
  const int jq = tid & 3;

  for (int s = jq * 96; s < jq * 96 + 96; ++s) {
    float a = tb;
#pragma unroll
    for (int h = 0; h < 16; ++h)
      a += fmaxf(h0L[r][h] + h1T[h][s], 0.f) * w0[h];
    Tl[r][s] = a;
  }
  __syncthreads();

  float acc[6] = {0, 0, 0, 0, 0, 0};
  for (int s0 = 0; s0 < RR; s0 += 4) {
    float4 tv = *(const float4*)&Tl[r][s0];
#pragma unroll
    for (int jj = 0; jj < 6; ++jj) {
      const float4 p0 = *(const float4*)&RP[jq * 6 + jj][s0];
      acc[jj] = fmaf(tv.x, p0.x, acc[jj]);
      acc[jj] = fmaf(tv.y, p0.y, acc[jj]);
      acc[jj] = fmaf(tv.z, p0.z, acc[jj]);
      acc[jj] = fmaf(tv.w, p0.w, acc[jj]);
    }
  }
  const int gr = chunk * 48 + r;
#pragma unroll
  for (int jj = 0; jj < 6; ++jj) {
    const int jp = jq * 6 + jj;
    const int j = jp + 1;
    part[r][j] = (j < K) ? RP[j][gr] * acc[jj] : 0.f;
  }
  __syncthreads();
  if (tid < MM) {
    const int j = tid;
    float s = 0.f;
    if (j >= 1) {
#pragma unroll 4
      for (int rr2 = 0; rr2 < 48; ++rr2) s += part[rr2][j];
    }
    bilinP[(size_t)(b * 8 + chunk) * MM + j] = s;
  }
}

// ---------------- Kernel D: linear-space alpha scan. 1 block/batch ----------
// Invariant: alpha_r = L + log(t[r]);  t' = (M · t/Z) ∘ exp(e), L += log Z.
__global__ __launch_bounds__(1024) void kD(
    const unsigned short* __restrict__ expb, const float* __restrict__ aff,
    const int* __restrict__ nreg, const int* __restrict__ mlist,
    const int* __restrict__ kcnt, const float* __restrict__ Em,
    const float* __restrict__ bilinP, float* __restrict__ result) {
  __shared__ unsigned short eHi[192 * RR];     // expT rows 192..383 (147456 B)
  __shared__ float tLds[2][RR];
  __shared__ float wmax[2][16];
  __shared__ float fred[16];

  const int b = blockIdx.x;
  const int tid = threadIdx.x;
  const int w = tid >> 6;
  const int lane = tid & 63;
  const int lam = lane & 15;
  const int g = lane >> 4;
  const int nr = nreg[b];
  const unsigned short* ebase = expb + (size_t)b * RR * RR;

  const int K = kcnt[b];
  if (K == 0) {
    if (tid == 0) result[b] = 0.f;
    return;
  }
  {  // stage rows 192..383 into LDS (first use is k=1, after k=0's barrier)
    const uint4* src = (const uint4*)(ebase + 192 * RR);
    uint4* dst = (uint4*)eHi;
    for (int i = tid; i < 192 * RR / 8; i += 1024) dst[i] = src[i];
  }

  const int myrow0 = w * 24;
  const bool hi = (w >= 8);
  float L = 0.f;

  auto LD = [&](int p, uint4* A) {
    const int row = myrow0 + p * 4 + g;
    if (hi) {
      const uint4* lp = (const uint4*)&eHi[(row - 192) * RR + lam * 24];
      A[0] = lp[0]; A[1] = lp[1]; A[2] = lp[2];
    } else {
      const uint4* gp = (const uint4*)(ebase + ((size_t)row * RR + lam * 24));
      A[0] = gp[0]; A[1] = gp[1]; A[2] = gp[2];
    }
  };

  for (int k = 0; k < K; ++k) {
    const int q = k & 1;
    const int m = mlist[b * MM + k];
    const float* arow = aff + ((size_t)(b * MM + m)) * RR;
    float ee[6];
#pragma unroll
    for (int p = 0; p < 6; ++p) ee[p] = __expf(arow[myrow0 + p * 4 + g]);

    float lmax = 0.f;                       // t >= 0 always
    if (k == 0) {
#pragma unroll
      for (int p = 0; p < 6; ++p) {
        const int row = myrow0 + p * 4 + g;
        const float t = (row < nr) ? ee[p] : 0.f;
        lmax = fmaxf(lmax, t);
        if (lam == 0) tLds[q][row] = t;
      }
    } else {
      float Z = wmax[q ^ 1][0];
#pragma unroll
      for (int i = 1; i < 16; ++i) Z = fmaxf(Z, wmax[q ^ 1][i]);
      const float invZ = 1.f / Z;
      L += __logf(Z);                       // off critical path, scalar
      float xr[24];
#pragma unroll
      for (int j4 = 0; j4 < 6; ++j4) {
        float4 v = *(const float4*)&tLds[q ^ 1][lam * 24 + j4 * 4];
        xr[j4 * 4 + 0] = v.x * invZ; xr[j4 * 4 + 1] = v.y * invZ;
        xr[j4 * 4 + 2] = v.z * invZ; xr[j4 * 4 + 3] = v.w * invZ;
      }
      uint4 bufA[3], bufB[3];
      LD(0, bufA);
      LD(1, bufB);
#pragma unroll
      for (int p = 0; p < 6; ++p) {
        uint4* cur = (p & 1) ? bufB : bufA;
        const unsigned dw[12] = {cur[0].x, cur[0].y, cur[0].z, cur[0].w,
                                 cur[1].x, cur[1].y, cur[1].z, cur[1].w,
                                 cur[2].x, cur[2].y, cur[2].z, cur[2].w};
        float ax = 0.f, ay = 0.f;
#pragma unroll
        for (int j = 0; j < 12; ++j) {
          ax = fmaf(__uint_as_float(dw[j] << 16), xr[2 * j], ax);
          ay = fmaf(__uint_as_float(dw[j] & 0xffff0000u), xr[2 * j + 1], ay);
        }
        if (p < 4) LD(p + 2, cur);          // depth-2 prefetch
        float asum = ax + ay;
#pragma unroll
        for (int off = 1; off < 16; off <<= 1) asum += __shfl_xor(asum, off);
        const float t = asum * ee[p];
        lmax = fmaxf(lmax, t);
        if (lam == 0) tLds[q][myrow0 + p * 4 + g] = t;
      }
    }
#pragma unroll
    for (int off = 32; off > 0; off >>= 1) lmax = fmaxf(lmax, __shfl_xor(lmax, off));
    if (lane == 0) wmax[q][w] = lmax;
    __syncthreads();
  }

  // epilogue: fwd = L + log(sum_r t_r); gold from precomputed bilin/Em
  const int qf = (K - 1) & 1;
  float fp = (tid < RR) ? tLds[qf][tid] : 0.f;
#pragma unroll
  for (int off = 32; off > 0; off >>= 1) fp += __shfl_xor(fp, off);
  if (lane == 0) fred[w] = fp;
  __syncthreads();
  if (tid == 0) {
    float fs = 0.f;
#pragma unroll
    for (int i = 0; i < 16; ++i) fs += fred[i];
    const float fwd = L + __logf(fs);
    float gold = Em[b * MM + mlist[b * MM + 0]];
    for (int j = 1; j < K; ++j) {
      float bil = 0.f;
#pragma unroll
      for (int c = 0; c < 8; ++c) bil += bilinP[(size_t)(b * 8 + c) * MM + j];
      gold += bil + Em[b * MM + mlist[b * MM + j]];
    }
    result[b] = fwd - gold;
  }
}

// ---------------- Kernel E: final deterministic reduction ----------
__global__ void kE(const float* __restrict__ result, const int* __restrict__ nmen,
                   float* __restrict__ out) {
  if (threadIdx.x == 0 && blockIdx.x == 0) {
    float s = 0.f;
    int d = 0;
    for (int b = 0; b < 32; ++b) { s += result[b]; d += nmen[b]; }
    if (d < 1) d = 1;
    out[0] = s / (float)d;
  }
}

extern "C" void kernel_launch(void* const* d_in, const int* in_sizes, int n_in,
                              void* d_out, int out_size, void* d_ws, size_t ws_size,
                              hipStream_t stream) {
  const float* region = (const float*)d_in[0];
  const float* aff    = (const float*)d_in[1];
  const float* gt     = (const float*)d_in[2];
  const int*   nmen   = (const int*)d_in[3];
  const int*   nreg   = (const int*)d_in[4];
  const float* t0w    = (const float*)d_in[5];
  const float* t0b    = (const float*)d_in[6];
  const float* t1w    = (const float*)d_in[7];
  const float* t1b    = (const float*)d_in[8];
  const float* trw    = (const float*)d_in[9];
  const float* trb    = (const float*)d_in[10];
  float* out = (float*)d_out;
  char* ws = (char*)d_ws;

  size_t off = 0;
  auto alloc = [&](size_t bytes) {
    void* p = ws + off;
    off += (bytes + 255) & ~(size_t)255;
    return p;
  };
  float*          h0h1   = (float*)alloc((size_t)BB * RR * 32 * 4);          // 1.57 MB
  unsigned short* expb   = (unsigned short*)alloc((size_t)BB * RR * RR * 2); // 9.44 MB
  float*          rsum   = (float*)alloc((size_t)BB * MM * 4);
  int*            mlist  = (int*)alloc((size_t)BB * MM * 4);
  int*            kcnt   = (int*)alloc((size_t)BB * 4);
  float*          Em     = (float*)alloc((size_t)BB * MM * 4);
  float*          bilinP = (float*)alloc((size_t)BB * 8 * MM * 4);
  float*          result = (float*)alloc((size_t)BB * 4);

  kA<<<(BB * RR) / 32, 256, 0, stream>>>(region, t0w, t0b, t1w, t1b, h0h1);
  kCM<<<BB, 64, 0, stream>>>(gt, aff, nmen, nreg, rsum, Em, mlist, kcnt);
  kT<<<256, 256, 0, stream>>>(h0h1, trw, trb, expb);
  kY<<<256, 192, 0, stream>>>(h0h1, trw, trb, gt, nreg, rsum, mlist, kcnt, bilinP);
  kD<<<BB, 1024, 0, stream>>>(expb, aff, nreg, mlist, kcnt, Em, bilinP, result);
  kE<<<1, 64, 0, stream>>>(result, nmen, out);
}

// Round 7
// 223.747 us; speedup vs baseline: 3.0065x; 1.0031x over previous
//
#include <hip/hip_runtime.h>

#define NEGV (-100000000.0f)
typedef __attribute__((ext_vector_type(2))) float f32x2;

constexpr int BB = 32, MM = 24, RR = 384, DD = 2048;

static __device__ __forceinline__ unsigned f2bf(float x) {  // RNE round to bf16
  union { float f; unsigned u; } v; v.f = x;
  return (v.u + 0x7fffu + ((v.u >> 16) & 1u)) >> 16;
}

// DPP helpers: row-scan add / max (VALU pipe, not DS). ctrl must be immediate.
template <int CTRL>
static __device__ __forceinline__ float dpp_add(float x) {
  int y = __builtin_amdgcn_update_dpp(0, __float_as_int(x), CTRL, 0xf, 0xf, true);
  return x + __int_as_float(y);
}
template <int CTRL>
static __device__ __forceinline__ float dpp_max(float x) {
  int y = __builtin_amdgcn_update_dpp(0, __float_as_int(x), CTRL, 0xf, 0xf, true);
  return fmaxf(x, __int_as_float(y));
}

// ---------------- Kernel A ----------------
__global__ __launch_bounds__(256) void kA(const float* __restrict__ region,
    const float* __restrict__ t0w, const float* __restrict__ t0b,
    const float* __restrict__ t1w, const float* __restrict__ t1b,
    float* __restrict__ h0h1) {
  __shared__ float rlds[32][260];
  __shared__ float wlds[256][36];
  const int t = threadIdx.x;
  const int r = t & 31;
  const int q = t >> 5;
  const int row0 = blockIdx.x * 32;
  float acc[32];
#pragma unroll
  for (int h = 0; h < 32; ++h) acc[h] = 0.f;

  for (int tile = 0; tile < 8; ++tile) {
    const int d0 = tile * 256;
    __syncthreads();
#pragma unroll
    for (int i = 0; i < 8; ++i) {
      int flat = i * 256 + t;
      int rr2 = flat >> 6;
      int cc = (flat & 63) << 2;
      *(float4*)&rlds[rr2][cc] =
          *(const float4*)(region + (size_t)(row0 + rr2) * DD + d0 + cc);
    }
#pragma unroll
    for (int h = 0; h < 32; ++h) {
      const float* wsrc = (h < 16) ? (t0w + (size_t)h * DD)
                                   : (t1w + (size_t)(h - 16) * DD);
      wlds[t][h] = wsrc[d0 + t];
    }
    __syncthreads();
    const int djb = q * 32;
#pragma unroll 4
    for (int dj = djb; dj < djb + 32; ++dj) {
      float rv = rlds[r][dj];
      const float4* wp = (const float4*)&wlds[dj][0];
#pragma unroll
      for (int h4 = 0; h4 < 8; ++h4) {
        float4 wv = wp[h4];
        acc[h4 * 4 + 0] = fmaf(rv, wv.x, acc[h4 * 4 + 0]);
        acc[h4 * 4 + 1] = fmaf(rv, wv.y, acc[h4 * 4 + 1]);
        acc[h4 * 4 + 2] = fmaf(rv, wv.z, acc[h4 * 4 + 2]);
        acc[h4 * 4 + 3] = fmaf(rv, wv.w, acc[h4 * 4 + 3]);
      }
    }
  }
  __syncthreads();
  float* red = &wlds[0][0];
#pragma unroll
  for (int h4 = 0; h4 < 8; ++h4) {
    *(float4*)&red[(q * 32 + r) * 36 + h4 * 4] =
        make_float4(acc[h4 * 4 + 0], acc[h4 * 4 + 1], acc[h4 * 4 + 2], acc[h4 * 4 + 3]);
  }
  __syncthreads();
  {
    const int r2 = t & 31;
    const int hb = (t >> 5) * 4;
    float s0 = 0, s1 = 0, s2 = 0, s3 = 0;
#pragma unroll
    for (int qq = 0; qq < 8; ++qq) {
      float4 v = *(const float4*)&red[(qq * 32 + r2) * 36 + hb];
      s0 += v.x; s1 += v.y; s2 += v.z; s3 += v.w;
    }
    float4 bias = (hb < 16) ? *(const float4*)(t0b + hb)
                            : *(const float4*)(t1b + hb - 16);
    *(float4*)(h0h1 + (size_t)(row0 + r2) * 32 + hb) =
        make_float4(s0 + bias.x, s1 + bias.y, s2 + bias.z, s3 + bias.w);
  }
}

// ---------------- Kernel T: expb[b][r][s] = exp(tran) in bf16 ----------------
__global__ __launch_bounds__(256) void kT(const float* __restrict__ h0h1,
    const float* __restrict__ trw, const float* __restrict__ trb,
    unsigned short* __restrict__ expb) {
  __shared__ float h1T[16][388];
  __shared__ float h0L[48][16];
  const int b = blockIdx.x & 31;
  const int chunk = blockIdx.x >> 5;
  const int r0 = chunk * 48;
  const int tid = threadIdx.x;

  for (int h = 0; h < 16; ++h)
    for (int s = tid; s < RR; s += 256)
      h1T[h][s] = h0h1[((size_t)b * RR + s) * 32 + 16 + h];
  for (int i = tid; i < 768; i += 256) {
    int row = i >> 4, h = i & 15;
    h0L[row][h] = h0h1[((size_t)b * RR + r0 + row) * 32 + h];
  }
  float w0[16];
#pragma unroll
  for (int h = 0; h < 16; ++h) w0[h] = trw[h];
  const float tb = trb[0];
  __syncthreads();

  const int lam = tid & 63;
  const int grp = tid >> 6;
  const int s0 = lam * 6;
  for (int p = 0; p < 12; ++p) {
    const int row = p * 4 + grp;
    float a0 = tb, a1 = tb, a2 = tb, a3 = tb, a4 = tb, a5 = tb;
#pragma unroll
    for (int h = 0; h < 16; ++h) {
      const float hx = h0L[row][h];
      const float wv = w0[h];
      float2 v0 = *(const float2*)&h1T[h][s0];
      float2 v1 = *(const float2*)&h1T[h][s0 + 2];
      float2 v2 = *(const float2*)&h1T[h][s0 + 4];
      a0 += fmaxf(hx + v0.x, 0.f) * wv;
      a1 += fmaxf(hx + v0.y, 0.f) * wv;
      a2 += fmaxf(hx + v1.x, 0.f) * wv;
      a3 += fmaxf(hx + v1.y, 0.f) * wv;
      a4 += fmaxf(hx + v2.x, 0.f) * wv;
      a5 += fmaxf(hx + v2.y, 0.f) * wv;
    }
    const size_t base = (size_t)(b * RR + r0 + row) * RR + s0;
    unsigned* oe = (unsigned*)(expb + base);
    oe[0] = f2bf(__expf(fminf(a0, 80.f))) | (f2bf(__expf(fminf(a1, 80.f))) << 16);
    oe[1] = f2bf(__expf(fminf(a2, 80.f))) | (f2bf(__expf(fminf(a3, 80.f))) << 16);
    oe[2] = f2bf(__expf(fminf(a4, 80.f))) | (f2bf(__expf(fminf(a5, 80.f))) << 16);
  }
}

// ---------------- Kernel CM: rsum + Em + compact active-m list --------------
__global__ __launch_bounds__(64) void kCM(const float* __restrict__ gt,
    const float* __restrict__ aff, const int* __restrict__ nmen,
    const int* __restrict__ nreg, float* __restrict__ rsum,
    float* __restrict__ Em, int* __restrict__ mlist, int* __restrict__ kcnt) {
  const int b = blockIdx.x;
  const int lane = threadIdx.x;
  const int nm = nmen[b], nr = nreg[b];
  int c = 0;
  for (int m = 0; m < MM; ++m) {
    const size_t bm = (size_t)(b * MM + m);
    float p = 0.f, t1 = 0.f, t2 = 0.f;
#pragma unroll
    for (int i = 0; i < 6; ++i) {
      int s = lane * 6 + i;
      float g = gt[bm * RR + s];
      float a = (g >= 0.5f && s < nr && m < nm) ? g : 0.f;
      float e = aff[bm * RR + s];
      p += a;
      t1 += a * e;
      t2 += (a > 0.f) ? a * __logf(a) : 0.f;
    }
#pragma unroll
    for (int off = 32; off > 0; off >>= 1) {
      p += __shfl_xor(p, off);
      t1 += __shfl_xor(t1, off);
      t2 += __shfl_xor(t2, off);
    }
    if (lane == 0) {
      rsum[bm] = p;
      Em[bm] = (p > 0.f) ? (t1 - t2) / p + __logf(p) : 0.f;
      if (p > 0.f) mlist[b * MM + (c++)] = m;
    }
  }
  if (lane == 0) {
    kcnt[b] = c;
    for (int j = c; j < MM; ++j) mlist[b * MM + j] = 0;
  }
}

// ---------------- Kernel Y: bilinP partials ---------------------------------
__global__ __launch_bounds__(192) void kY(const float* __restrict__ h0h1,
    const float* __restrict__ trw, const float* __restrict__ trb,
    const float* __restrict__ gt, const int* __restrict__ nreg,
    const float* __restrict__ rsum, const int* __restrict__ mlist,
    const int* __restrict__ kcnt, float* __restrict__ bilinP) {
  __shared__ float h1T[16][388];
  __shared__ float h0L[48][16];
  __shared__ float Tl[48][388];
  __shared__ float RP[MM][392];
  __shared__ float part[48][26];
  const int b = blockIdx.x & 31;
  const int chunk = blockIdx.x >> 5;
  const int r0 = chunk * 48;
  const int tid = threadIdx.x;
  const int K = kcnt[b];
  const int nr = nreg[b];

  for (int h = 0; h < 16; ++h)
    for (int s = tid; s < RR; s += 192)
      h1T[h][s] = h0h1[((size_t)b * RR + s) * 32 + 16 + h];
  for (int i = tid; i < 768; i += 192) {
    int row = i >> 4, h = i & 15;
    h0L[row][h] = h0h1[((size_t)b * RR + r0 + row) * 32 + h];
  }
  for (int j = 0; j < MM; ++j) {
    if (j < K) {
      int m = mlist[b * MM + j];
      float inv = 1.f / rsum[b * MM + m];
      for (int s = tid; s < RR; s += 192) {
        float g = gt[((size_t)(b * MM + m)) * RR + s];
        RP[j][s] = (g >= 0.5f && s < nr) ? g * inv : 0.f;
      }
    } else {
      for (int s = tid; s < RR; s += 192) RP[j][s] = 0.f;
    }
  }
  float w0[16];
#pragma unroll
  for (int h = 0; h < 16; ++h) w0[h] = trw[h];
  const float tb = trb[0];
  __syncthreads();

  const int r = tid >> 2;
  const int jq = tid & 3;

  for (int s = jq * 96; s < jq * 96 + 96; ++s) {
    float a = tb;
#pragma unroll
    for (int h = 0; h < 16; ++h)
      a += fmaxf(h0L[r][h] + h1T[h][s], 0.f) * w0[h];
    Tl[r][s] = a;
  }
  __syncthreads();

  float acc[6] = {0, 0, 0, 0, 0, 0};
  for (int s0 = 0; s0 < RR; s0 += 4) {
    float4 tv = *(const float4*)&Tl[r][s0];
#pragma unroll
    for (int jj = 0; jj < 6; ++jj) {
      const float4 p0 = *(const float4*)&RP[jq * 6 + jj][s0];
      acc[jj] = fmaf(tv.x, p0.x, acc[jj]);
      acc[jj] = fmaf(tv.y, p0.y, acc[jj]);
      acc[jj] = fmaf(tv.z, p0.z, acc[jj]);
      acc[jj] = fmaf(tv.w, p0.w, acc[jj]);
    }
  }
  const int gr = chunk * 48 + r;
#pragma unroll
  for (int jj = 0; jj < 6; ++jj) {
    const int jp = jq * 6 + jj;
    const int j = jp + 1;
    part[r][j] = (j < K) ? RP[j][gr] * acc[jj] : 0.f;
  }
  __syncthreads();
  if (tid < MM) {
    const int j = tid;
    float s = 0.f;
    if (j >= 1) {
#pragma unroll 4
      for (int rr2 = 0; rr2 < 48; ++rr2) s += part[rr2][j];
    }
    bilinP[(size_t)(b * 8 + chunk) * MM + j] = s;
  }
}

// ---------------- Kernel D: linear-space scan, DPP reductions ---------------
__global__ __launch_bounds__(1024) void kD(
    const unsigned short* __restrict__ expb, const float* __restrict__ aff,
    const int* __restrict__ nreg, const int* __restrict__ mlist,
    const int* __restrict__ kcnt, const float* __restrict__ Em,
    const float* __restrict__ bilinP, float* __restrict__ result) {
  __shared__ unsigned short eHi[192 * RR];     // expT rows 192..383 (147456 B)
  __shared__ float tL[2][16][28];              // padded t storage
  __shared__ float wmax[2][16];
  __shared__ float fred[16];

  const int b = blockIdx.x;
  const int tid = threadIdx.x;
  const int w = tid >> 6;
  const int lane = tid & 63;
  const int lam = lane & 15;
  const int g = lane >> 4;
  const int nr = nreg[b];
  const unsigned short* ebase = expb + (size_t)b * RR * RR;

  const int K = kcnt[b];
  if (K == 0) {
    if (tid == 0) result[b] = 0.f;
    return;
  }

  const int myrow0 = w * 24;
  const bool hi = (w >= 8);

  // prefetch step-0 emissions early
  float eraw[6];
  {
    const int m0 = mlist[b * MM];
    const float* arow = aff + ((size_t)(b * MM + m0)) * RR;
#pragma unroll
    for (int p = 0; p < 6; ++p) eraw[p] = arow[myrow0 + p * 4 + g];
  }

  {  // stage rows 192..383 into LDS (first consumed at k=1, after k=0 barrier)
    const uint4* src = (const uint4*)(ebase + 192 * RR);
    uint4* dst = (uint4*)eHi;
    for (int i = tid; i < 192 * RR / 8; i += 1024) dst[i] = src[i];
  }

  float L = 0.f;

  auto LD = [&](int p, uint4* A) {
    const int row = myrow0 + p * 4 + g;
    if (hi) {
      const uint4* lp = (const uint4*)&eHi[(row - 192) * RR + lam * 24];
      A[0] = lp[0]; A[1] = lp[1]; A[2] = lp[2];
    } else {
      const uint4* gp = (const uint4*)(ebase + ((size_t)row * RR + lam * 24));
      A[0] = gp[0]; A[1] = gp[1]; A[2] = gp[2];
    }
  };

  for (int k = 0; k < K; ++k) {
    const int q = k & 1;

    // prefetch next step's emission row (hides L2 latency under this step)
    float nraw[6];
    if (k + 1 < K) {
      const int mn = mlist[b * MM + k + 1];
      const float* arow = aff + ((size_t)(b * MM + mn)) * RR;
#pragma unroll
      for (int p = 0; p < 6; ++p) nraw[p] = arow[myrow0 + p * 4 + g];
    }

    float lmaxv = 0.f;                       // t >= 0 always
    if (k == 0) {
      float ee[6];
#pragma unroll
      for (int p = 0; p < 6; ++p) ee[p] = __expf(eraw[p]);
#pragma unroll
      for (int p = 0; p < 6; ++p) {
        const int row = myrow0 + p * 4 + g;
        const float t = (row < nr) ? ee[p] : 0.f;
        if (lam == 15) {
          tL[q][w][p * 4 + g] = t;
          lmaxv = fmaxf(lmaxv, t);
        }
      }
    } else {
      // Z from previous step's block max; fold 1/Z into the emission factor
      const float4* wm4 = (const float4*)&wmax[q ^ 1][0];
      float4 m0 = wm4[0], m1 = wm4[1], m2 = wm4[2], m3 = wm4[3];
      float4 mm01 = make_float4(fmaxf(m0.x, m1.x), fmaxf(m0.y, m1.y),
                                fmaxf(m0.z, m1.z), fmaxf(m0.w, m1.w));
      float4 mm23 = make_float4(fmaxf(m2.x, m3.x), fmaxf(m2.y, m3.y),
                                fmaxf(m2.z, m3.z), fmaxf(m2.w, m3.w));
      const float Z = fmaxf(fmaxf(fmaxf(mm01.x, mm01.y), fmaxf(mm01.z, mm01.w)),
                            fmaxf(fmaxf(mm23.x, mm23.y), fmaxf(mm23.z, mm23.w)));
      const float invZ = 1.f / Z;
      L += __logf(Z);
      float eeZ[6];
#pragma unroll
      for (int p = 0; p < 6; ++p) eeZ[p] = __expf(eraw[p]) * invZ;

      // xr: previous t values for my 24-column chunk (raw, scale folded above)
      f32x2 xr2[12];
#pragma unroll
      for (int j4 = 0; j4 < 6; ++j4) {
        float4 v = *(const float4*)&tL[q ^ 1][lam][j4 * 4];
        f32x2 lo, hiw;
        lo.x = v.x; lo.y = v.y; hiw.x = v.z; hiw.y = v.w;
        xr2[j4 * 2] = lo;
        xr2[j4 * 2 + 1] = hiw;
      }

      uint4 bufA[3], bufB[3];
      LD(0, bufA);
      LD(1, bufB);
#pragma unroll
      for (int p = 0; p < 6; ++p) {
        uint4* cur = (p & 1) ? bufB : bufA;
        const unsigned dw[12] = {cur[0].x, cur[0].y, cur[0].z, cur[0].w,
                                 cur[1].x, cur[1].y, cur[1].z, cur[1].w,
                                 cur[2].x, cur[2].y, cur[2].z, cur[2].w};
        f32x2 acc;
        acc.x = 0.f; acc.y = 0.f;
#pragma unroll
        for (int j = 0; j < 12; ++j) {
          f32x2 mmv;
          mmv.x = __uint_as_float(dw[j] << 16);
          mmv.y = __uint_as_float(dw[j] & 0xffff0000u);
          acc += mmv * xr2[j];                 // v_pk_fma_f32
        }
        if (p < 4) LD(p + 2, cur);             // depth-2 prefetch
        float asum = acc.x + acc.y;
        // 16-lane inclusive scan (VALU DPP): total lands at lam==15
        asum = dpp_add<0x111>(asum);
        asum = dpp_add<0x112>(asum);
        asum = dpp_add<0x114>(asum);
        asum = dpp_add<0x118>(asum);
        const float t = asum * eeZ[p];
        if (lam == 15) {
          tL[q][w][p * 4 + g] = t;
          lmaxv = fmaxf(lmaxv, t);
        }
      }
    }
    // wave max of lmaxv (valid at lam==15 lanes; 0 elsewhere) via DPP
    lmaxv = dpp_max<0x111>(lmaxv);
    lmaxv = dpp_max<0x112>(lmaxv);
    lmaxv = dpp_max<0x114>(lmaxv);
    lmaxv = dpp_max<0x118>(lmaxv);
    lmaxv = dpp_max<0x142>(lmaxv);             // bcast15
    lmaxv = dpp_max<0x143>(lmaxv);             // bcast31
    if (lane == 63) wmax[q][w] = lmaxv;
#pragma unroll
    for (int p = 0; p < 6; ++p) eraw[p] = nraw[p];
    __syncthreads();
  }

  // epilogue: fwd = L + log(sum_r t_r); gold from precomputed bilin/Em
  const int qf = (K - 1) & 1;
  float fp = (tid < RR) ? tL[qf][tid / 24][tid % 24] : 0.f;
#pragma unroll
  for (int off = 32; off > 0; off >>= 1) fp += __shfl_xor(fp, off);
  if (lane == 0) fred[w] = fp;
  __syncthreads();
  if (tid == 0) {
    float fs = 0.f;
#pragma unroll
    for (int i = 0; i < 16; ++i) fs += fred[i];
    const float fwd = L + __logf(fs);
    float gold = Em[b * MM + mlist[b * MM + 0]];
    for (int j = 1; j < K; ++j) {
      float bil = 0.f;
#pragma unroll
      for (int c = 0; c < 8; ++c) bil += bilinP[(size_t)(b * 8 + c) * MM + j];
      gold += bil + Em[b * MM + mlist[b * MM + j]];
    }
    result[b] = fwd - gold;
  }
}

// ---------------- Kernel E: final deterministic reduction ----------
__global__ void kE(const float* __restrict__ result, const int* __restrict__ nmen,
                   float* __restrict__ out) {
  if (threadIdx.x == 0 && blockIdx.x == 0) {
    float s = 0.f;
    int d = 0;
    for (int b = 0; b < 32; ++b) { s += result[b]; d += nmen[b]; }
    if (d < 1) d = 1;
    out[0] = s / (float)d;
  }
}

extern "C" void kernel_launch(void* const* d_in, const int* in_sizes, int n_in,
                              void* d_out, int out_size, void* d_ws, size_t ws_size,
                              hipStream_t stream) {
  const float* region = (const float*)d_in[0];
  const float* aff    = (const float*)d_in[1];
  const float* gt     = (const float*)d_in[2];
  const int*   nmen   = (const int*)d_in[3];
  const int*   nreg   = (const int*)d_in[4];
  const float* t0w    = (const float*)d_in[5];
  const float* t0b    = (const float*)d_in[6];
  const float* t1w    = (const float*)d_in[7];
  const float* t1b    = (const float*)d_in[8];
  const float* trw    = (const float*)d_in[9];
  const float* trb    = (const float*)d_in[10];
  float* out = (float*)d_out;
  char* ws = (char*)d_ws;

  size_t off = 0;
  auto alloc = [&](size_t bytes) {
    void* p = ws + off;
    off += (bytes + 255) & ~(size_t)255;
    return p;
  };
  float*          h0h1   = (float*)alloc((size_t)BB * RR * 32 * 4);          // 1.57 MB
  unsigned short* expb   = (unsigned short*)alloc((size_t)BB * RR * RR * 2); // 9.44 MB
  float*          rsum   = (float*)alloc((size_t)BB * MM * 4);
  int*            mlist  = (int*)alloc((size_t)BB * MM * 4);
  int*            kcnt   = (int*)alloc((size_t)BB * 4);
  float*          Em     = (float*)alloc((size_t)BB * MM * 4);
  float*          bilinP = (float*)alloc((size_t)BB * 8 * MM * 4);
  float*          result = (float*)alloc((size_t)BB * 4);

  kA<<<(BB * RR) / 32, 256, 0, stream>>>(region, t0w, t0b, t1w, t1b, h0h1);
  kCM<<<BB, 64, 0, stream>>>(gt, aff, nmen, nreg, rsum, Em, mlist, kcnt);
  kT<<<256, 256, 0, stream>>>(h0h1, trw, trb, expb);
  kY<<<256, 192, 0, stream>>>(h0h1, trw, trb, gt, nreg, rsum, mlist, kcnt, bilinP);
  kD<<<BB, 1024, 0, stream>>>(expb, aff, nreg, mlist, kcnt, Em, bilinP, result);
  kE<<<1, 64, 0, stream>>>(result, nmen, out);
}